// Round 18
// baseline (1230.029 us; speedup 1.0000x reference)
//
#include <hip/hip_runtime.h>
#include <hip/hip_bf16.h>
#include <cstdint>
#include <cstddef>

typedef __attribute__((ext_vector_type(8))) short short8;
typedef __attribute__((ext_vector_type(4))) float f32x4;
typedef __attribute__((ext_vector_type(4))) float f4;
typedef __attribute__((ext_vector_type(4))) short s4;
typedef __attribute__((ext_vector_type(4))) unsigned u32x4;
typedef unsigned short u16;
typedef unsigned long long u64;

#define VOCAB 32000
#define EMB   512
#define HID   1024
#define GDIM  4096   // 4*HID
#define BATCH 16
#define SEQ   256
#define MTOT  4096   // BATCH*SEQ
#define NBLK  64     // lstm blocks

// tagged path (r10 fallback)
#define SLAB  4096          // bytes per producer slab (1KB data + 3KB pad)
#define BUFB  (NBLK * SLAB) // bytes per h buffer (256 KB)

// sentinel-arena path (r17-validated, 674 us)
#define SLAB2  1024                  // 512 B data + 512 B pad
#define STEPB2 (NBLK * SLAB2)        // 64 KB per step buffer
#define ARENAB ((size_t)SEQ * STEPB2) // 16 MB, write-once

static __device__ __forceinline__ u16 f2bf(float f) {
  unsigned u = __builtin_bit_cast(unsigned, f);
  u += 0x7fffu + ((u >> 16) & 1u);   // RNE
  return (u16)(u >> 16);
}

static __device__ __forceinline__ float fsig(float x) {
  return __builtin_amdgcn_rcpf(1.f + __expf(-x));
}
static __device__ __forceinline__ float ftanh(float x) {
  return 1.f - 2.f * __builtin_amdgcn_rcpf(1.f + __expf(2.f * x));
}

__global__ void cvt_bf16_v4(const float* __restrict__ in, u16* __restrict__ out, long n4) {
  long i = (long)blockIdx.x * blockDim.x + threadIdx.x;
  long stride = (long)gridDim.x * blockDim.x;
  for (; i < n4; i += stride) {
    f4 v = reinterpret_cast<const f4*>(in)[i];
    s4 o;
#pragma unroll
    for (int j = 0; j < 4; ++j) o[j] = (short)f2bf(v[j]);
    reinterpret_cast<s4*>(out)[i] = o;
  }
}

__global__ void embed_gather(const int* __restrict__ x, const float* __restrict__ emb,
                             u16* __restrict__ A) {
  int m = blockIdx.x;                 // m = b*SEQ + t
  long base = (long)x[m] * EMB;
  int e4 = threadIdx.x;               // 0..127, 4 elems each
  f4 v = reinterpret_cast<const f4*>(emb + base)[e4];
  s4 o;
#pragma unroll
  for (int j = 0; j < 4; ++j) o[j] = (short)f2bf(v[j]);
  reinterpret_cast<s4*>(A + (long)m * EMB)[e4] = o;
}

static __device__ __forceinline__ void gload_lds16(const void* g, void* l) {
  __builtin_amdgcn_global_load_lds(
      (const __attribute__((address_space(1))) void*)g,
      (__attribute__((address_space(3))) void*)l, 16, 0, 0);
}

// C = A*B^T + bias, 128x128 tile, BK=64, swizzled staging [r10-validated].
// NEW (r18): bx-MAJOR traversal after XCD chunking — each XCD's concurrent
// blocks share ONE B-panel (L2-resident) and stream A (L3-resident), so B
// leaves HBM ~once instead of M/128 times. NEW: nt epilogue stores keep the
// out-stream from evicting B/A panels in L3.
// TXG=1: out row = t*BATCH + b (time-major xg).
template<int TXG>
__global__ __launch_bounds__(256) void gemm_bt(
    const u16* __restrict__ A, const u16* __restrict__ B,
    const float* __restrict__ bias, float* __restrict__ C,
    int M, int N, int K)
{
  __shared__ u16 As[128 * 64];
  __shared__ u16 Bs[128 * 64];
  int tid  = threadIdx.x;
  int lane = tid & 63;
  int wid  = tid >> 6;

  // XCD chunking on the raw dispatch id, then bx-major decomposition:
  // consecutive blocks within an XCD share bx (same B panel).
  int nwg = gridDim.x * gridDim.y;                 // must be % 8 == 0
  int raw = blockIdx.y * gridDim.x + blockIdx.x;
  int id2 = (raw & 7) * (nwg >> 3) + (raw >> 3);
  int bx  = id2 / gridDim.y, by = id2 % gridDim.y;
  int m0 = by * 128, n0 = bx * 128;

  int wm = (wid >> 1) * 64, wn = (wid & 1) * 64;
  int r  = lane & 15;
  int hi = lane >> 4;
  f32x4 acc[4][4] = {};

  const u16* gaj[4];
  const u16* gbj[4];
  u16* laj[4];
  u16* lbj[4];
#pragma unroll
  for (int j = 0; j < 4; ++j) {
    int c   = wid * 256 + j * 64 + lane;
    int row = c >> 3;
    int gl  = (c & 7) ^ (row & 7);
    gaj[j] = A + (long)(m0 + row) * K + gl * 8;
    gbj[j] = B + (long)(n0 + row) * K + gl * 8;
    laj[j] = As + wid * 2048 + j * 512;
    lbj[j] = Bs + wid * 2048 + j * 512;
  }

  for (int kt = 0; kt < K; kt += 64) {
    __syncthreads();
#pragma unroll
    for (int j = 0; j < 4; ++j) {
      gload_lds16(gaj[j] + kt, laj[j]);
      gload_lds16(gbj[j] + kt, lbj[j]);
    }
    __syncthreads();
    short8 af[2][4], bf[2][4];
#pragma unroll
    for (int ks = 0; ks < 2; ++ks)
#pragma unroll
      for (int i = 0; i < 4; ++i) {
        int ra = wm + i * 16 + r;
        int rb = wn + i * 16 + r;
        af[ks][i] = *reinterpret_cast<const short8*>(
            &As[ra * 64 + ((ks * 4 + hi) ^ (ra & 7)) * 8]);
        bf[ks][i] = *reinterpret_cast<const short8*>(
            &Bs[rb * 64 + ((ks * 4 + hi) ^ (rb & 7)) * 8]);
      }
#pragma unroll
    for (int ks = 0; ks < 2; ++ks)
#pragma unroll
      for (int i = 0; i < 4; ++i)
#pragma unroll
        for (int j = 0; j < 4; ++j)
          acc[i][j] = __builtin_amdgcn_mfma_f32_16x16x32_bf16(
              af[ks][i], bf[ks][j], acc[i][j], 0, 0, 0);
  }

#pragma unroll
  for (int i = 0; i < 4; ++i) {
    int m = m0 + wm + i * 16 + (hi << 2);
#pragma unroll
    for (int j = 0; j < 4; ++j) {
      int n = n0 + wn + j * 16 + r;
      float bv = bias[n];
#pragma unroll
      for (int jj = 0; jj < 4; ++jj) {
        int mm = m + jj;
        long row;
        if constexpr (TXG) {
          row = (long)(mm & (SEQ - 1)) * BATCH + (mm >> 8);  // t*B + b
        } else {
          row = mm;
        }
        float v = acc[i][j][jj] + bv;
        const float* dst = &C[row * N + n];
        asm volatile("global_store_dword %0, %1, off nt"
                     :: "v"(dst), "v"(v) : "memory");
      }
    }
  }
}

// ============ LSTM: sentinel-arena (r17-validated, 674 us) ==============
__global__ __launch_bounds__(256, 1) void lstm_arena(
    const float* __restrict__ xg, const u16* __restrict__ Whh,
    const float* __restrict__ b_hh, char* __restrict__ hsb,
    u16* __restrict__ h_all)
{
  __shared__ float part[4][4][16][17];
  __shared__ u16 htile[16][16];

  int tid = threadIdx.x;
  int w = tid >> 6, lane = tid & 63;
  int bid = blockIdx.x;
  int col0 = bid * 16;
  int r  = lane & 15;
  int ko = (lane >> 4) << 3;          // 0,8,16,24

  short8 Wf[8][4];
#pragma unroll
  for (int kk8 = 0; kk8 < 8; ++kk8)
#pragma unroll
    for (int g = 0; g < 4; ++g)
      Wf[kk8][g] = *reinterpret_cast<const short8*>(
          Whh + (long)(g * HID + col0 + r) * HID + (w * 256 + kk8 * 32 + ko));

  unsigned coff[2][4];
#pragma unroll
  for (int ph = 0; ph < 2; ++ph)
#pragma unroll
    for (int kk = 0; kk < 4; ++kk) {
      int p = w * 16 + (ph * 4 + kk) * 2 + (ko >> 4);
      coff[ph][kk] = (unsigned)(p * SLAB2 + r * 32 + (ko & 15) * 2);
    }

  int eb = tid >> 4, ec = tid & 15;
  const float* xgp = xg + (long)eb * GDIM + col0 + ec;
  float bias4[4];
#pragma unroll
  for (int g = 0; g < 4; ++g) bias4[g] = b_hh[g * HID + col0 + ec];
  u16* hap = h_all + (long)eb * SEQ * HID + col0 + ec;
  float creg = 0.f;

  if (tid < 32) {
    short8 z = {};
    void* dst = hsb + (size_t)bid * SLAB2 + tid * 16;
    asm volatile("global_store_dwordx4 %0, %1, off sc1" :: "v"(dst), "v"(z) : "memory");
  }

  float xv[4];
#pragma unroll
  for (int g = 0; g < 4; ++g) xv[g] = xgp[g * HID];

  for (int t = 0; t < SEQ; ++t) {
    const char* hb = hsb + (size_t)t * STEPB2;

    f32x4 a0 = {}, a1 = {}, a2 = {}, a3 = {};
#pragma unroll
    for (int ph = 0; ph < 2; ++ph) {
      u32x4 q[4];
      for (;;) {
#pragma unroll
        for (int kk = 0; kk < 4; ++kk)
          asm volatile("global_load_dwordx4 %0, %1, off sc1"
                       : "=v"(q[kk]) : "v"(hb + coff[ph][kk]));
        asm volatile("s_waitcnt vmcnt(0)" ::: "memory");
        __builtin_amdgcn_sched_barrier(0);
        bool ok = true;
#pragma unroll
        for (int kk = 0; kk < 4; ++kk)
#pragma unroll
          for (int j = 0; j < 4; ++j) {
            unsigned v = q[kk][j];
            ok = ok && ((v & 0xffffu) != 0xffffu) && ((v >> 16) != 0xffffu);
          }
        if (__all(ok)) break;
        __builtin_amdgcn_s_sleep(1);
      }
#pragma unroll
      for (int kk = 0; kk < 4; ++kk) {
        short8 av = __builtin_bit_cast(short8, q[kk]);
        a0 = __builtin_amdgcn_mfma_f32_16x16x32_bf16(av, Wf[ph * 4 + kk][0], a0, 0, 0, 0);
        a1 = __builtin_amdgcn_mfma_f32_16x16x32_bf16(av, Wf[ph * 4 + kk][1], a1, 0, 0, 0);
        a2 = __builtin_amdgcn_mfma_f32_16x16x32_bf16(av, Wf[ph * 4 + kk][2], a2, 0, 0, 0);
        a3 = __builtin_amdgcn_mfma_f32_16x16x32_bf16(av, Wf[ph * 4 + kk][3], a3, 0, 0, 0);
      }
    }

#pragma unroll
    for (int j = 0; j < 4; ++j) {
      int batch = ((lane >> 4) << 2) + j;
      part[w][0][batch][r] = a0[j];
      part[w][1][batch][r] = a1[j];
      part[w][2][batch][r] = a2[j];
      part[w][3][batch][r] = a3[j];
    }
    __syncthreads();                       // (A) partials + h(t) reads done

    float pre[4];
#pragma unroll
    for (int g = 0; g < 4; ++g)
      pre[g] = part[0][g][eb][ec] + part[1][g][eb][ec] +
               part[2][g][eb][ec] + part[3][g][eb][ec] + xv[g] + bias4[g];
    float i_ = fsig(pre[0]);
    float f_ = fsig(pre[1]);
    float g_ = ftanh(pre[2]);
    float o_ = fsig(pre[3]);
    float cn = f_ * creg + i_ * g_;
    creg = cn;
    u16 hbf = f2bf(o_ * ftanh(cn));
    htile[eb][ec] = hbf;
    __syncthreads();                       // (B) htile complete

    if (t + 1 < SEQ && tid < 32) {         // publish h(t+1), fire-and-forget
      short8 v = *reinterpret_cast<const short8*>(
          reinterpret_cast<const u16*>(htile) + tid * 8);
      void* dst = hsb + (size_t)(t + 1) * STEPB2 + (size_t)bid * SLAB2 + tid * 16;
      asm volatile("global_store_dwordx4 %0, %1, off sc1" :: "v"(dst), "v"(v) : "memory");
    }

    hap[(long)t * HID] = hbf;
    int tn = (t + 1 < SEQ) ? t + 1 : t;
#pragma unroll
    for (int g = 0; g < 4; ++g)
      xv[g] = xgp[(long)tn * BATCH * GDIM + g * HID];
  }
}

extern "C" void kernel_launch(void* const* d_in, const int* in_sizes, int n_in,
                              void* d_out, int out_size, void* d_ws, size_t ws_size,
                              hipStream_t stream) {
  const int*   x      = (const int*)d_in[0];
  const float* emb    = (const float*)d_in[1];
  const float* W_ih   = (const float*)d_in[2];
  const float* W_hh   = (const float*)d_in[3];
  const float* b_ih   = (const float*)d_in[4];
  const float* b_hh   = (const float*)d_in[5];
  const float* head_W = (const float*)d_in[6];
  const float* head_b = (const float*)d_in[7];
  float* out = (float*)d_out;

  char* ws = (char*)d_ws;
  size_t off = 0;
  auto alloc = [&](size_t bytes) -> void* {
    void* p = ws + off;
    off += (bytes + 255) & ~(size_t)255;
    return p;
  };
  u16*   Aemb  = (u16*)alloc((size_t)MTOT * EMB * 2);
  u16*   Wih_b = (u16*)alloc((size_t)GDIM * EMB * 2);
  u16*   Whh_b = (u16*)alloc((size_t)GDIM * HID * 2);
  u16*   HW_b  = (u16*)alloc((size_t)VOCAB * HID * 2);
  float* xg    = (float*)alloc((size_t)MTOT * GDIM * 4);   // time-major [T][B][4H]
  u16*   h_all = (u16*)alloc((size_t)MTOT * HID * 2);
  char*  hsb   = (char*)alloc(ARENAB);                     // 16 MB h arena

  hipMemsetAsync(hsb, 0xFF, ARENAB, stream);   // sentinels (fail closed)

  cvt_bf16_v4<<<1024, 256, 0, stream>>>(W_ih, Wih_b, (long)GDIM * EMB / 4);
  cvt_bf16_v4<<<1024, 256, 0, stream>>>(W_hh, Whh_b, (long)GDIM * HID / 4);
  cvt_bf16_v4<<<2048, 256, 0, stream>>>(head_W, HW_b, (long)VOCAB * HID / 4);
  embed_gather<<<MTOT, 128, 0, stream>>>(x, emb, Aemb);

  gemm_bt<1><<<dim3(GDIM / 128, MTOT / 128), 256, 0, stream>>>(
      Aemb, Wih_b, b_ih, xg, MTOT, GDIM, EMB);

  lstm_arena<<<dim3(NBLK), dim3(256), 0, stream>>>(
      xg, Whh_b, b_hh, hsb, h_all);

  gemm_bt<0><<<dim3(VOCAB / 128, MTOT / 128), 256, 0, stream>>>(
      h_all, HW_b, head_b, out, MTOT, VOCAB, HID);
}

// Round 19
// 1189.788 us; speedup vs baseline: 1.0338x; 1.0338x over previous
//
#include <hip/hip_runtime.h>
#include <hip/hip_bf16.h>
#include <cstdint>
#include <cstddef>

typedef __attribute__((ext_vector_type(8))) short short8;
typedef __attribute__((ext_vector_type(4))) float f32x4;
typedef __attribute__((ext_vector_type(4))) float f4;
typedef __attribute__((ext_vector_type(4))) short s4;
typedef __attribute__((ext_vector_type(4))) unsigned u32x4;
typedef unsigned short u16;
typedef unsigned long long u64;

#define VOCAB 32000
#define EMB   512
#define HID   1024
#define GDIM  4096   // 4*HID
#define BATCH 16
#define SEQ   256
#define MTOT  4096   // BATCH*SEQ
#define NBLK  64     // lstm blocks

// sentinel-arena h exchange (r17-validated, 674 us)
#define SLAB2  1024                  // 512 B data + 512 B pad
#define STEPB2 (NBLK * SLAB2)        // 64 KB per step buffer
#define ARENAB ((size_t)SEQ * STEPB2) // 16 MB, write-once

static __device__ __forceinline__ u16 f2bf(float f) {
  unsigned u = __builtin_bit_cast(unsigned, f);
  u += 0x7fffu + ((u >> 16) & 1u);   // RNE
  return (u16)(u >> 16);
}

static __device__ __forceinline__ float fsig(float x) {
  return __builtin_amdgcn_rcpf(1.f + __expf(-x));
}
static __device__ __forceinline__ float ftanh(float x) {
  return 1.f - 2.f * __builtin_amdgcn_rcpf(1.f + __expf(2.f * x));
}

// one launch for all three weight converts (saves launch gaps + tail waste)
__global__ void cvt_bf16_all(
    const float* __restrict__ i0, u16* __restrict__ o0, long n0,
    const float* __restrict__ i1, u16* __restrict__ o1, long n1,
    const float* __restrict__ i2, u16* __restrict__ o2, long n2)
{
  long i = (long)blockIdx.x * blockDim.x + threadIdx.x;
  long stride = (long)gridDim.x * blockDim.x;
  long total = n0 + n1 + n2;
  for (; i < total; i += stride) {
    const float* in; u16* out; long j;
    if (i < n0)           { in = i0; out = o0; j = i; }
    else if (i < n0 + n1) { in = i1; out = o1; j = i - n0; }
    else                  { in = i2; out = o2; j = i - n0 - n1; }
    f4 v = reinterpret_cast<const f4*>(in)[j];
    s4 o;
#pragma unroll
    for (int k = 0; k < 4; ++k) o[k] = (short)f2bf(v[k]);
    reinterpret_cast<s4*>(out)[j] = o;
  }
}

__global__ void embed_gather(const int* __restrict__ x, const float* __restrict__ emb,
                             u16* __restrict__ A) {
  int m = blockIdx.x;                 // m = b*SEQ + t
  long base = (long)x[m] * EMB;
  int e4 = threadIdx.x;               // 0..127, 4 elems each
  f4 v = reinterpret_cast<const f4*>(emb + base)[e4];
  s4 o;
#pragma unroll
  for (int j = 0; j < 4; ++j) o[j] = (short)f2bf(v[j]);
  reinterpret_cast<s4*>(A + (long)m * EMB)[e4] = o;
}

static __device__ __forceinline__ void gload_lds16(const void* g, void* l) {
  __builtin_amdgcn_global_load_lds(
      (const __attribute__((address_space(1))) void*)g,
      (__attribute__((address_space(3))) void*)l, 16, 0, 0);
}

// C = A*B^T + bias, 128x128 tile, BK=64, swizzled staging, r17 traversal
// (bx-fastest within XCD chunk — A panel L2-resident per XCD).
// TXG=1 (xg): out row = t*BATCH+b, NORMAL stores (LSTM reads xg from L3).
// TXG=0 (head): nt stores — out is a terminal 512MB stream; keep it from
// evicting the B panels in L3.
template<int TXG>
__global__ __launch_bounds__(256) void gemm_bt(
    const u16* __restrict__ A, const u16* __restrict__ B,
    const float* __restrict__ bias, float* __restrict__ C,
    int M, int N, int K)
{
  __shared__ u16 As[128 * 64];
  __shared__ u16 Bs[128 * 64];
  int tid  = threadIdx.x;
  int lane = tid & 63;
  int wid  = tid >> 6;

  int nwg = gridDim.x * gridDim.y;                 // % 8 == 0 at both sites
  int id  = blockIdx.y * gridDim.x + blockIdx.x;
  int id2 = (id & 7) * (nwg >> 3) + (id >> 3);
  int bx  = id2 % gridDim.x, by = id2 / gridDim.x;
  int m0 = by * 128, n0 = bx * 128;

  int wm = (wid >> 1) * 64, wn = (wid & 1) * 64;
  int r  = lane & 15;
  int hi = lane >> 4;
  f32x4 acc[4][4] = {};

  const u16* gaj[4];
  const u16* gbj[4];
  u16* laj[4];
  u16* lbj[4];
#pragma unroll
  for (int j = 0; j < 4; ++j) {
    int c   = wid * 256 + j * 64 + lane;
    int row = c >> 3;
    int gl  = (c & 7) ^ (row & 7);
    gaj[j] = A + (long)(m0 + row) * K + gl * 8;
    gbj[j] = B + (long)(n0 + row) * K + gl * 8;
    laj[j] = As + wid * 2048 + j * 512;
    lbj[j] = Bs + wid * 2048 + j * 512;
  }

  for (int kt = 0; kt < K; kt += 64) {
    __syncthreads();
#pragma unroll
    for (int j = 0; j < 4; ++j) {
      gload_lds16(gaj[j] + kt, laj[j]);
      gload_lds16(gbj[j] + kt, lbj[j]);
    }
    __syncthreads();
    short8 af[2][4], bf[2][4];
#pragma unroll
    for (int ks = 0; ks < 2; ++ks)
#pragma unroll
      for (int i = 0; i < 4; ++i) {
        int ra = wm + i * 16 + r;
        int rb = wn + i * 16 + r;
        af[ks][i] = *reinterpret_cast<const short8*>(
            &As[ra * 64 + ((ks * 4 + hi) ^ (ra & 7)) * 8]);
        bf[ks][i] = *reinterpret_cast<const short8*>(
            &Bs[rb * 64 + ((ks * 4 + hi) ^ (rb & 7)) * 8]);
      }
#pragma unroll
    for (int ks = 0; ks < 2; ++ks)
#pragma unroll
      for (int i = 0; i < 4; ++i)
#pragma unroll
        for (int j = 0; j < 4; ++j)
          acc[i][j] = __builtin_amdgcn_mfma_f32_16x16x32_bf16(
              af[ks][i], bf[ks][j], acc[i][j], 0, 0, 0);
  }

#pragma unroll
  for (int i = 0; i < 4; ++i) {
    int m = m0 + wm + i * 16 + (hi << 2);
#pragma unroll
    for (int j = 0; j < 4; ++j) {
      int n = n0 + wn + j * 16 + r;
      float bv = bias[n];
#pragma unroll
      for (int jj = 0; jj < 4; ++jj) {
        int mm = m + jj;
        float v = acc[i][j][jj] + bv;
        if constexpr (TXG) {
          long row = (long)(mm & (SEQ - 1)) * BATCH + (mm >> 8);  // t*B + b
          C[row * N + n] = v;                    // normal store: L3-resident
        } else {
          const float* dst = &C[(long)mm * N + n];
          asm volatile("global_store_dword %0, %1, off nt"
                       :: "v"(dst), "v"(v) : "memory");
        }
      }
    }
  }
}

// ============ LSTM: sentinel-arena (r17-validated, 674 us) ==============
__global__ __launch_bounds__(256, 1) void lstm_arena(
    const float* __restrict__ xg, const u16* __restrict__ Whh,
    const float* __restrict__ b_hh, char* __restrict__ hsb,
    u16* __restrict__ h_all)
{
  __shared__ float part[4][4][16][17];
  __shared__ u16 htile[16][16];

  int tid = threadIdx.x;
  int w = tid >> 6, lane = tid & 63;
  int bid = blockIdx.x;
  int col0 = bid * 16;
  int r  = lane & 15;
  int ko = (lane >> 4) << 3;          // 0,8,16,24

  short8 Wf[8][4];
#pragma unroll
  for (int kk8 = 0; kk8 < 8; ++kk8)
#pragma unroll
    for (int g = 0; g < 4; ++g)
      Wf[kk8][g] = *reinterpret_cast<const short8*>(
          Whh + (long)(g * HID + col0 + r) * HID + (w * 256 + kk8 * 32 + ko));

  unsigned coff[2][4];
#pragma unroll
  for (int ph = 0; ph < 2; ++ph)
#pragma unroll
    for (int kk = 0; kk < 4; ++kk) {
      int p = w * 16 + (ph * 4 + kk) * 2 + (ko >> 4);
      coff[ph][kk] = (unsigned)(p * SLAB2 + r * 32 + (ko & 15) * 2);
    }

  int eb = tid >> 4, ec = tid & 15;
  const float* xgp = xg + (long)eb * GDIM + col0 + ec;
  float bias4[4];
#pragma unroll
  for (int g = 0; g < 4; ++g) bias4[g] = b_hh[g * HID + col0 + ec];
  u16* hap = h_all + (long)eb * SEQ * HID + col0 + ec;
  float creg = 0.f;

  if (tid < 32) {
    short8 z = {};
    void* dst = hsb + (size_t)bid * SLAB2 + tid * 16;
    asm volatile("global_store_dwordx4 %0, %1, off sc1" :: "v"(dst), "v"(z) : "memory");
  }

  float xv[4];
#pragma unroll
  for (int g = 0; g < 4; ++g) xv[g] = xgp[g * HID];

  for (int t = 0; t < SEQ; ++t) {
    const char* hb = hsb + (size_t)t * STEPB2;

    f32x4 a0 = {}, a1 = {}, a2 = {}, a3 = {};
#pragma unroll
    for (int ph = 0; ph < 2; ++ph) {
      u32x4 q[4];
      for (;;) {
#pragma unroll
        for (int kk = 0; kk < 4; ++kk)
          asm volatile("global_load_dwordx4 %0, %1, off sc1"
                       : "=v"(q[kk]) : "v"(hb + coff[ph][kk]));
        asm volatile("s_waitcnt vmcnt(0)" ::: "memory");
        __builtin_amdgcn_sched_barrier(0);
        bool ok = true;
#pragma unroll
        for (int kk = 0; kk < 4; ++kk)
#pragma unroll
          for (int j = 0; j < 4; ++j) {
            unsigned v = q[kk][j];
            ok = ok && ((v & 0xffffu) != 0xffffu) && ((v >> 16) != 0xffffu);
          }
        if (__all(ok)) break;
        __builtin_amdgcn_s_sleep(1);
      }
#pragma unroll
      for (int kk = 0; kk < 4; ++kk) {
        short8 av = __builtin_bit_cast(short8, q[kk]);
        a0 = __builtin_amdgcn_mfma_f32_16x16x32_bf16(av, Wf[ph * 4 + kk][0], a0, 0, 0, 0);
        a1 = __builtin_amdgcn_mfma_f32_16x16x32_bf16(av, Wf[ph * 4 + kk][1], a1, 0, 0, 0);
        a2 = __builtin_amdgcn_mfma_f32_16x16x32_bf16(av, Wf[ph * 4 + kk][2], a2, 0, 0, 0);
        a3 = __builtin_amdgcn_mfma_f32_16x16x32_bf16(av, Wf[ph * 4 + kk][3], a3, 0, 0, 0);
      }
    }

#pragma unroll
    for (int j = 0; j < 4; ++j) {
      int batch = ((lane >> 4) << 2) + j;
      part[w][0][batch][r] = a0[j];
      part[w][1][batch][r] = a1[j];
      part[w][2][batch][r] = a2[j];
      part[w][3][batch][r] = a3[j];
    }
    __syncthreads();                       // (A) partials + h(t) reads done

    float pre[4];
#pragma unroll
    for (int g = 0; g < 4; ++g)
      pre[g] = part[0][g][eb][ec] + part[1][g][eb][ec] +
               part[2][g][eb][ec] + part[3][g][eb][ec] + xv[g] + bias4[g];
    float i_ = fsig(pre[0]);
    float f_ = fsig(pre[1]);
    float g_ = ftanh(pre[2]);
    float o_ = fsig(pre[3]);
    float cn = f_ * creg + i_ * g_;
    creg = cn;
    u16 hbf = f2bf(o_ * ftanh(cn));
    htile[eb][ec] = hbf;
    __syncthreads();                       // (B) htile complete

    if (t + 1 < SEQ && tid < 32) {         // publish h(t+1), fire-and-forget
      short8 v = *reinterpret_cast<const short8*>(
          reinterpret_cast<const u16*>(htile) + tid * 8);
      void* dst = hsb + (size_t)(t + 1) * STEPB2 + (size_t)bid * SLAB2 + tid * 16;
      asm volatile("global_store_dwordx4 %0, %1, off sc1" :: "v"(dst), "v"(v) : "memory");
    }

    hap[(long)t * HID] = hbf;
    int tn = (t + 1 < SEQ) ? t + 1 : t;
#pragma unroll
    for (int g = 0; g < 4; ++g)
      xv[g] = xgp[(long)tn * BATCH * GDIM + g * HID];
  }
}

extern "C" void kernel_launch(void* const* d_in, const int* in_sizes, int n_in,
                              void* d_out, int out_size, void* d_ws, size_t ws_size,
                              hipStream_t stream) {
  const int*   x      = (const int*)d_in[0];
  const float* emb    = (const float*)d_in[1];
  const float* W_ih   = (const float*)d_in[2];
  const float* W_hh   = (const float*)d_in[3];
  const float* b_ih   = (const float*)d_in[4];
  const float* b_hh   = (const float*)d_in[5];
  const float* head_W = (const float*)d_in[6];
  const float* head_b = (const float*)d_in[7];
  float* out = (float*)d_out;

  char* ws = (char*)d_ws;
  size_t off = 0;
  auto alloc = [&](size_t bytes) -> void* {
    void* p = ws + off;
    off += (bytes + 255) & ~(size_t)255;
    return p;
  };
  u16*   Aemb  = (u16*)alloc((size_t)MTOT * EMB * 2);
  u16*   Wih_b = (u16*)alloc((size_t)GDIM * EMB * 2);
  u16*   Whh_b = (u16*)alloc((size_t)GDIM * HID * 2);
  u16*   HW_b  = (u16*)alloc((size_t)VOCAB * HID * 2);
  float* xg    = (float*)alloc((size_t)MTOT * GDIM * 4);   // time-major [T][B][4H]
  u16*   h_all = (u16*)alloc((size_t)MTOT * HID * 2);
  char*  hsb   = (char*)alloc(ARENAB);                     // 16 MB h arena

  hipMemsetAsync(hsb, 0xFF, ARENAB, stream);   // sentinels (fail closed)

  cvt_bf16_all<<<2048, 256, 0, stream>>>(
      W_ih,   Wih_b, (long)GDIM * EMB / 4,
      W_hh,   Whh_b, (long)GDIM * HID / 4,
      head_W, HW_b,  (long)VOCAB * HID / 4);
  embed_gather<<<MTOT, 128, 0, stream>>>(x, emb, Aemb);

  gemm_bt<1><<<dim3(GDIM / 128, MTOT / 128), 256, 0, stream>>>(
      Aemb, Wih_b, b_ih, xg, MTOT, GDIM, EMB);

  lstm_arena<<<dim3(NBLK), dim3(256), 0, stream>>>(
      xg, Whh_b, b_hh, hsb, h_all);

  gemm_bt<0><<<dim3(VOCAB / 128, MTOT / 128), 256, 0, stream>>>(
      h_all, HW_b, head_b, out, MTOT, VOCAB, HID);
}

// Round 20
// 1171.528 us; speedup vs baseline: 1.0499x; 1.0156x over previous
//
#include <hip/hip_runtime.h>
#include <hip/hip_bf16.h>
#include <cstdint>
#include <cstddef>

typedef __attribute__((ext_vector_type(8))) short short8;
typedef __attribute__((ext_vector_type(4))) float f32x4;
typedef __attribute__((ext_vector_type(4))) float f4;
typedef __attribute__((ext_vector_type(4))) short s4;
typedef __attribute__((ext_vector_type(4))) unsigned u32x4;
typedef unsigned short u16;
typedef unsigned long long u64;

#define VOCAB 32000
#define EMB   512
#define HID   1024
#define GDIM  4096   // 4*HID
#define BATCH 16
#define SEQ   256
#define MTOT  4096   // BATCH*SEQ
#define NBLK  64     // lstm blocks

// tagged path (r10 fallback, only if arena doesn't fit ws)
#define SLAB  4096          // bytes per producer slab (1KB data + 3KB pad)
#define BUFB  (NBLK * SLAB) // bytes per h buffer (256 KB)

// sentinel-arena path (r17-validated)
#define SLAB2  1024                  // 512 B data + 512 B pad
#define STEPB2 (NBLK * SLAB2)        // 64 KB per step buffer
#define ARENAB ((size_t)SEQ * STEPB2) // 16 MB, write-once

static __device__ __forceinline__ u16 f2bf(float f) {
  unsigned u = __builtin_bit_cast(unsigned, f);
  u += 0x7fffu + ((u >> 16) & 1u);   // RNE
  return (u16)(u >> 16);
}

static __device__ __forceinline__ float fsig(float x) {
  return __builtin_amdgcn_rcpf(1.f + __expf(-x));
}
static __device__ __forceinline__ float ftanh(float x) {
  return 1.f - 2.f * __builtin_amdgcn_rcpf(1.f + __expf(2.f * x));
}

__global__ void cvt_bf16_v4(const float* __restrict__ in, u16* __restrict__ out, long n4) {
  long i = (long)blockIdx.x * blockDim.x + threadIdx.x;
  long stride = (long)gridDim.x * blockDim.x;
  for (; i < n4; i += stride) {
    f4 v = reinterpret_cast<const f4*>(in)[i];
    s4 o;
#pragma unroll
    for (int j = 0; j < 4; ++j) o[j] = (short)f2bf(v[j]);
    reinterpret_cast<s4*>(out)[i] = o;
  }
}

__global__ void embed_gather(const int* __restrict__ x, const float* __restrict__ emb,
                             u16* __restrict__ A) {
  int m = blockIdx.x;                 // m = b*SEQ + t
  long base = (long)x[m] * EMB;
  int e4 = threadIdx.x;               // 0..127, 4 elems each
  f4 v = reinterpret_cast<const f4*>(emb + base)[e4];
  s4 o;
#pragma unroll
  for (int j = 0; j < 4; ++j) o[j] = (short)f2bf(v[j]);
  reinterpret_cast<s4*>(A + (long)m * EMB)[e4] = o;
}

static __device__ __forceinline__ void gload_lds16(const void* g, void* l) {
  __builtin_amdgcn_global_load_lds(
      (const __attribute__((address_space(1))) void*)g,
      (__attribute__((address_space(3))) void*)l, 16, 0, 0);
}

// C = A*B^T + bias, 128x128 tile, BK=64, swizzled staging, bijective XCD
// grid swizzle (r17 traversal). TXG=1: out row = t*BATCH + b (time-major xg).
template<int TXG>
__global__ __launch_bounds__(256) void gemm_bt(
    const u16* __restrict__ A, const u16* __restrict__ B,
    const float* __restrict__ bias, float* __restrict__ C,
    int M, int N, int K)
{
  __shared__ u16 As[128 * 64];
  __shared__ u16 Bs[128 * 64];
  int tid  = threadIdx.x;
  int lane = tid & 63;
  int wid  = tid >> 6;

  int nwg = gridDim.x * gridDim.y;                 // % 8 == 0 at both sites
  int id  = blockIdx.y * gridDim.x + blockIdx.x;
  int id2 = (id & 7) * (nwg >> 3) + (id >> 3);
  int bx  = id2 % gridDim.x, by = id2 / gridDim.x;
  int m0 = by * 128, n0 = bx * 128;

  int wm = (wid >> 1) * 64, wn = (wid & 1) * 64;
  int r  = lane & 15;
  int hi = lane >> 4;
  f32x4 acc[4][4] = {};

  const u16* gaj[4];
  const u16* gbj[4];
  u16* laj[4];
  u16* lbj[4];
#pragma unroll
  for (int j = 0; j < 4; ++j) {
    int c   = wid * 256 + j * 64 + lane;
    int row = c >> 3;
    int gl  = (c & 7) ^ (row & 7);
    gaj[j] = A + (long)(m0 + row) * K + gl * 8;
    gbj[j] = B + (long)(n0 + row) * K + gl * 8;
    laj[j] = As + wid * 2048 + j * 512;
    lbj[j] = Bs + wid * 2048 + j * 512;
  }

  for (int kt = 0; kt < K; kt += 64) {
    __syncthreads();
#pragma unroll
    for (int j = 0; j < 4; ++j) {
      gload_lds16(gaj[j] + kt, laj[j]);
      gload_lds16(gbj[j] + kt, lbj[j]);
    }
    __syncthreads();
    short8 af[2][4], bf[2][4];
#pragma unroll
    for (int ks = 0; ks < 2; ++ks)
#pragma unroll
      for (int i = 0; i < 4; ++i) {
        int ra = wm + i * 16 + r;
        int rb = wn + i * 16 + r;
        af[ks][i] = *reinterpret_cast<const short8*>(
            &As[ra * 64 + ((ks * 4 + hi) ^ (ra & 7)) * 8]);
        bf[ks][i] = *reinterpret_cast<const short8*>(
            &Bs[rb * 64 + ((ks * 4 + hi) ^ (rb & 7)) * 8]);
      }
#pragma unroll
    for (int ks = 0; ks < 2; ++ks)
#pragma unroll
      for (int i = 0; i < 4; ++i)
#pragma unroll
        for (int j = 0; j < 4; ++j)
          acc[i][j] = __builtin_amdgcn_mfma_f32_16x16x32_bf16(
              af[ks][i], bf[ks][j], acc[i][j], 0, 0, 0);
  }

#pragma unroll
  for (int i = 0; i < 4; ++i) {
    int m = m0 + wm + i * 16 + (hi << 2);
#pragma unroll
    for (int j = 0; j < 4; ++j) {
      int n = n0 + wn + j * 16 + r;
      float bv = bias[n];
#pragma unroll
      for (int jj = 0; jj < 4; ++jj) {
        int mm = m + jj;
        long row;
        if constexpr (TXG) {
          row = (long)(mm & (SEQ - 1)) * BATCH + (mm >> 8);  // t*B + b
        } else {
          row = mm;
        }
        C[row * N + n] = acc[i][j][jj] + bv;
      }
    }
  }
}

// ============ LSTM variant A: sentinel-arena, MERGED single-poll =========
// r17 structure with the two load phases fused: all 8 x 16B chunk loads of
// h(t) issue together, ONE vmcnt(0) + sentinel vote certifies the step, then
// 32 MFMAs. Halves the serial coherence round-trips per step (2 -> 1).
__global__ __launch_bounds__(256, 1) void lstm_arena(
    const float* __restrict__ xg, const u16* __restrict__ Whh,
    const float* __restrict__ b_hh, char* __restrict__ hsb,
    u16* __restrict__ h_all)
{
  __shared__ float part[4][4][16][17];
  __shared__ u16 htile[16][16];

  int tid = threadIdx.x;
  int w = tid >> 6, lane = tid & 63;
  int bid = blockIdx.x;
  int col0 = bid * 16;
  int r  = lane & 15;
  int ko = (lane >> 4) << 3;          // 0,8,16,24

  short8 Wf[8][4];
#pragma unroll
  for (int kk8 = 0; kk8 < 8; ++kk8)
#pragma unroll
    for (int g = 0; g < 4; ++g)
      Wf[kk8][g] = *reinterpret_cast<const short8*>(
          Whh + (long)(g * HID + col0 + r) * HID + (w * 256 + kk8 * 32 + ko));

  // chunk offsets: k-chunk kk8 covers k = w*256 + kk8*32 + ko
  unsigned coff[8];
#pragma unroll
  for (int kk8 = 0; kk8 < 8; ++kk8) {
    int p = w * 16 + kk8 * 2 + (ko >> 4);
    coff[kk8] = (unsigned)(p * SLAB2 + r * 32 + (ko & 15) * 2);
  }

  int eb = tid >> 4, ec = tid & 15;
  const float* xgp = xg + (long)eb * GDIM + col0 + ec;
  float bias4[4];
#pragma unroll
  for (int g = 0; g < 4; ++g) bias4[g] = b_hh[g * HID + col0 + ec];
  u16* hap = h_all + (long)eb * SEQ * HID + col0 + ec;
  float creg = 0.f;

  if (tid < 32) {
    short8 z = {};
    void* dst = hsb + (size_t)bid * SLAB2 + tid * 16;
    asm volatile("global_store_dwordx4 %0, %1, off sc1" :: "v"(dst), "v"(z) : "memory");
  }

  float xv[4];
#pragma unroll
  for (int g = 0; g < 4; ++g) xv[g] = xgp[g * HID];

  for (int t = 0; t < SEQ; ++t) {
    const char* hb = hsb + (size_t)t * STEPB2;

    // ---- ONE bulk poll: 8 x 16B loads, one drain, one vote ----
    u32x4 q[8];
    for (;;) {
#pragma unroll
      for (int kk = 0; kk < 8; ++kk)
        asm volatile("global_load_dwordx4 %0, %1, off sc1"
                     : "=v"(q[kk]) : "v"(hb + coff[kk]));
      asm volatile("s_waitcnt vmcnt(0)" ::: "memory");
      __builtin_amdgcn_sched_barrier(0);
      bool ok = true;
#pragma unroll
      for (int kk = 0; kk < 8; ++kk)
#pragma unroll
        for (int j = 0; j < 4; ++j) {
          unsigned v = q[kk][j];
          ok = ok && ((v & 0xffffu) != 0xffffu) && ((v >> 16) != 0xffffu);
        }
      if (__all(ok)) break;
      __builtin_amdgcn_s_sleep(1);
    }

    f32x4 a0 = {}, a1 = {}, a2 = {}, a3 = {};
#pragma unroll
    for (int kk = 0; kk < 8; ++kk) {
      short8 av = __builtin_bit_cast(short8, q[kk]);
      a0 = __builtin_amdgcn_mfma_f32_16x16x32_bf16(av, Wf[kk][0], a0, 0, 0, 0);
      a1 = __builtin_amdgcn_mfma_f32_16x16x32_bf16(av, Wf[kk][1], a1, 0, 0, 0);
      a2 = __builtin_amdgcn_mfma_f32_16x16x32_bf16(av, Wf[kk][2], a2, 0, 0, 0);
      a3 = __builtin_amdgcn_mfma_f32_16x16x32_bf16(av, Wf[kk][3], a3, 0, 0, 0);
    }

#pragma unroll
    for (int j = 0; j < 4; ++j) {
      int batch = ((lane >> 4) << 2) + j;
      part[w][0][batch][r] = a0[j];
      part[w][1][batch][r] = a1[j];
      part[w][2][batch][r] = a2[j];
      part[w][3][batch][r] = a3[j];
    }
    __syncthreads();                       // (A) partials + h(t) reads done

    float pre[4];
#pragma unroll
    for (int g = 0; g < 4; ++g)
      pre[g] = part[0][g][eb][ec] + part[1][g][eb][ec] +
               part[2][g][eb][ec] + part[3][g][eb][ec] + xv[g] + bias4[g];
    float i_ = fsig(pre[0]);
    float f_ = fsig(pre[1]);
    float g_ = ftanh(pre[2]);
    float o_ = fsig(pre[3]);
    float cn = f_ * creg + i_ * g_;
    creg = cn;
    u16 hbf = f2bf(o_ * ftanh(cn));
    htile[eb][ec] = hbf;
    __syncthreads();                       // (B) htile complete

    if (t + 1 < SEQ && tid < 32) {         // publish h(t+1), fire-and-forget
      short8 v = *reinterpret_cast<const short8*>(
          reinterpret_cast<const u16*>(htile) + tid * 8);
      void* dst = hsb + (size_t)(t + 1) * STEPB2 + (size_t)bid * SLAB2 + tid * 16;
      asm volatile("global_store_dwordx4 %0, %1, off sc1" :: "v"(dst), "v"(v) : "memory");
    }

    hap[(long)t * HID] = hbf;
    int tn = (t + 1 < SEQ) ? t + 1 : t;
#pragma unroll
    for (int g = 0; g < 4; ++g)
      xv[g] = xgp[(long)tn * BATCH * GDIM + g * HID];
    // no end barrier: write-once buffers, htile WAR ordered by sync(A)@t+1
  }
}

// ============ LSTM variant B: r10 tagged (fallback if arena won't fit) ===
__global__ __launch_bounds__(256, 1) void lstm_persist(
    const float* __restrict__ xg, const u16* __restrict__ Whh,
    const float* __restrict__ b_hh, unsigned* __restrict__ h_buf,
    u16* __restrict__ h_all)
{
  __shared__ float part[4][4][16][17];

  int tid = threadIdx.x;
  int w = tid >> 6, lane = tid & 63;
  int bid = blockIdx.x;
  int col0 = bid * 16;
  int r  = lane & 15;
  int ko = (lane >> 4) << 3;

  short8 Wf[8][4];
#pragma unroll
  for (int kk8 = 0; kk8 < 8; ++kk8)
#pragma unroll
    for (int g = 0; g < 4; ++g)
      Wf[kk8][g] = *reinterpret_cast<const short8*>(
          Whh + (long)(g * HID + col0 + r) * HID + (w * 256 + kk8 * 32 + ko));

  unsigned soff[2][4];
#pragma unroll
  for (int ph = 0; ph < 2; ++ph)
#pragma unroll
    for (int kk = 0; kk < 4; ++kk) {
      int p = w * 16 + ph * 8 + kk * 2 + (ko >> 4);
      soff[ph][kk] = (unsigned)(p * SLAB + r * 64 + (ko & 8) * 4);
    }
  const char* hbase = reinterpret_cast<const char*>(h_buf);

  int eb = tid >> 4, ec = tid & 15;
  const float* xgp = xg + (long)eb * GDIM + col0 + ec;
  float bias4[4];
#pragma unroll
  for (int g = 0; g < 4; ++g) bias4[g] = b_hh[g * HID + col0 + ec];
  u16* hap = h_all + (long)eb * SEQ * HID + col0 + ec;
  float creg = 0.f;

  __hip_atomic_store(&h_buf[(bid * SLAB / 4) + tid], 1u << 16,
                     __ATOMIC_RELAXED, __HIP_MEMORY_SCOPE_AGENT);

  float xv[4];
#pragma unroll
  for (int g = 0; g < 4; ++g) xv[g] = xgp[g * HID];

  for (int t = 0; t < SEQ; ++t) {
    unsigned want = (unsigned)(t + 1);
    const char* hb = hbase + ((t & 1) ? BUFB : 0);

    f32x4 a0 = {}, a1 = {}, a2 = {}, a3 = {};
#pragma unroll
    for (int ph = 0; ph < 2; ++ph) {
      u32x4 q[4][2];
      for (;;) {
#pragma unroll
        for (int kk = 0; kk < 4; ++kk) {
          const void* a = hb + soff[ph][kk];
          const void* b = hb + soff[ph][kk] + 16;
          asm volatile("global_load_dwordx4 %0, %1, off sc1"
                       : "=v"(q[kk][0]) : "v"(a));
          asm volatile("global_load_dwordx4 %0, %1, off sc1"
                       : "=v"(q[kk][1]) : "v"(b));
        }
        asm volatile("s_waitcnt vmcnt(0)" ::: "memory");
        __builtin_amdgcn_sched_barrier(0);
        bool allok = true;
#pragma unroll
        for (int kk = 0; kk < 4; ++kk)
#pragma unroll
          for (int v = 0; v < 2; ++v)
#pragma unroll
            for (int j = 0; j < 4; ++j)
              allok = allok && ((q[kk][v][j] >> 16) >= want);
        if (__all(allok)) break;
        __builtin_amdgcn_s_sleep(1);
      }
#pragma unroll
      for (int kk = 0; kk < 4; ++kk) {
        u32x4 wv;
        wv[0] = (q[kk][0][0] & 0xffffu) | (q[kk][0][1] << 16);
        wv[1] = (q[kk][0][2] & 0xffffu) | (q[kk][0][3] << 16);
        wv[2] = (q[kk][1][0] & 0xffffu) | (q[kk][1][1] << 16);
        wv[3] = (q[kk][1][2] & 0xffffu) | (q[kk][1][3] << 16);
        short8 av = __builtin_bit_cast(short8, wv);
        a0 = __builtin_amdgcn_mfma_f32_16x16x32_bf16(av, Wf[ph * 4 + kk][0], a0, 0, 0, 0);
        a1 = __builtin_amdgcn_mfma_f32_16x16x32_bf16(av, Wf[ph * 4 + kk][1], a1, 0, 0, 0);
        a2 = __builtin_amdgcn_mfma_f32_16x16x32_bf16(av, Wf[ph * 4 + kk][2], a2, 0, 0, 0);
        a3 = __builtin_amdgcn_mfma_f32_16x16x32_bf16(av, Wf[ph * 4 + kk][3], a3, 0, 0, 0);
      }
    }

#pragma unroll
    for (int j = 0; j < 4; ++j) {
      int batch = ((lane >> 4) << 2) + j;
      part[w][0][batch][r] = a0[j];
      part[w][1][batch][r] = a1[j];
      part[w][2][batch][r] = a2[j];
      part[w][3][batch][r] = a3[j];
    }
    __syncthreads();

    float pre[4];
#pragma unroll
    for (int g = 0; g < 4; ++g)
      pre[g] = part[0][g][eb][ec] + part[1][g][eb][ec] +
               part[2][g][eb][ec] + part[3][g][eb][ec] + xv[g] + bias4[g];
    float i_ = fsig(pre[0]);
    float f_ = fsig(pre[1]);
    float g_ = ftanh(pre[2]);
    float o_ = fsig(pre[3]);
    float cn = f_ * creg + i_ * g_;
    creg = cn;
    u16 hbf = f2bf(o_ * ftanh(cn));

    if (t + 1 < SEQ) {
      unsigned word = (unsigned)hbf | ((unsigned)(t + 2) << 16);
      __hip_atomic_store(
          &h_buf[(((t + 1) & 1) ? BUFB / 4 : 0) + (bid * SLAB / 4) + tid],
          word, __ATOMIC_RELAXED, __HIP_MEMORY_SCOPE_AGENT);
    }

    hap[(long)t * HID] = hbf;
    int tn = (t + 1 < SEQ) ? t + 1 : t;
#pragma unroll
    for (int g = 0; g < 4; ++g)
      xv[g] = xgp[(long)tn * BATCH * GDIM + g * HID];

    __syncthreads();
  }
}

extern "C" void kernel_launch(void* const* d_in, const int* in_sizes, int n_in,
                              void* d_out, int out_size, void* d_ws, size_t ws_size,
                              hipStream_t stream) {
  const int*   x      = (const int*)d_in[0];
  const float* emb    = (const float*)d_in[1];
  const float* W_ih   = (const float*)d_in[2];
  const float* W_hh   = (const float*)d_in[3];
  const float* b_ih   = (const float*)d_in[4];
  const float* b_hh   = (const float*)d_in[5];
  const float* head_W = (const float*)d_in[6];
  const float* head_b = (const float*)d_in[7];
  float* out = (float*)d_out;

  char* ws = (char*)d_ws;
  size_t off = 0;
  auto alloc = [&](size_t bytes) -> void* {
    void* p = ws + off;
    off += (bytes + 255) & ~(size_t)255;
    return p;
  };
  u16*   Aemb  = (u16*)alloc((size_t)MTOT * EMB * 2);
  u16*   Wih_b = (u16*)alloc((size_t)GDIM * EMB * 2);
  u16*   Whh_b = (u16*)alloc((size_t)GDIM * HID * 2);
  u16*   HW_b  = (u16*)alloc((size_t)VOCAB * HID * 2);
  float* xg    = (float*)alloc((size_t)MTOT * GDIM * 4);   // time-major [T][B][4H]
  u16*   h_all = (u16*)alloc((size_t)MTOT * HID * 2);

  size_t off_arena = off;
  bool use_arena = (off_arena + ARENAB + 256 <= ws_size);

  cvt_bf16_v4<<<1024, 256, 0, stream>>>(W_ih, Wih_b, (long)GDIM * EMB / 4);
  cvt_bf16_v4<<<1024, 256, 0, stream>>>(W_hh, Whh_b, (long)GDIM * HID / 4);
  cvt_bf16_v4<<<2048, 256, 0, stream>>>(head_W, HW_b, (long)VOCAB * HID / 4);
  embed_gather<<<MTOT, 128, 0, stream>>>(x, emb, Aemb);

  gemm_bt<1><<<dim3(GDIM / 128, MTOT / 128), 256, 0, stream>>>(
      Aemb, Wih_b, b_ih, xg, MTOT, GDIM, EMB);

  if (use_arena) {
    char* hsb = (char*)alloc(ARENAB);
    hipMemsetAsync(hsb, 0xFF, ARENAB, stream);   // sentinels (fail closed)
    lstm_arena<<<dim3(NBLK), dim3(256), 0, stream>>>(
        xg, Whh_b, b_hh, hsb, h_all);
  } else {
    unsigned* h_buf = (unsigned*)alloc((size_t)2 * BUFB);
    hipMemsetAsync(h_buf, 0, (size_t)2 * BUFB, stream);   // tags fail closed
    lstm_persist<<<dim3(NBLK), dim3(256), 0, stream>>>(
        xg, Whh_b, b_hh, h_buf, h_all);
  }

  gemm_bt<0><<<dim3(VOCAB / 128, MTOT / 128), 256, 0, stream>>>(
      h_all, HW_b, head_b, out, MTOT, VOCAB, HID);
}

// Round 21
// 1143.808 us; speedup vs baseline: 1.0754x; 1.0242x over previous
//
#include <hip/hip_runtime.h>
#include <hip/hip_bf16.h>
#include <cstdint>
#include <cstddef>

typedef __attribute__((ext_vector_type(8))) short short8;
typedef __attribute__((ext_vector_type(4))) float f32x4;
typedef __attribute__((ext_vector_type(4))) float f4;
typedef __attribute__((ext_vector_type(4))) short s4;
typedef __attribute__((ext_vector_type(4))) unsigned u32x4;
typedef unsigned short u16;
typedef unsigned long long u64;

#define VOCAB 32000
#define EMB   512
#define HID   1024
#define GDIM  4096   // 4*HID
#define BATCH 16
#define SEQ   256
#define MTOT  4096   // BATCH*SEQ
#define NBLK  64     // lstm blocks

// tagged path (r10 fallback)
#define SLAB  4096          // bytes per producer slab (1KB data + 3KB pad)
#define BUFB  (NBLK * SLAB) // bytes per h buffer (256 KB)

// sentinel-arena path
#define SLAB2  1024                  // 512 B data + 512 B pad
#define STEPB2 (NBLK * SLAB2)        // 64 KB per step buffer
#define ARENAB ((size_t)SEQ * STEPB2) // 16 MB, write-once

static __device__ __forceinline__ u16 f2bf(float f) {
  unsigned u = __builtin_bit_cast(unsigned, f);
  u += 0x7fffu + ((u >> 16) & 1u);   // RNE
  return (u16)(u >> 16);
}

static __device__ __forceinline__ float fsig(float x) {
  return __builtin_amdgcn_rcpf(1.f + __expf(-x));
}
static __device__ __forceinline__ float ftanh(float x) {
  return 1.f - 2.f * __builtin_amdgcn_rcpf(1.f + __expf(2.f * x));
}

__global__ void cvt_bf16_v4(const float* __restrict__ in, u16* __restrict__ out, long n4) {
  long i = (long)blockIdx.x * blockDim.x + threadIdx.x;
  long stride = (long)gridDim.x * blockDim.x;
  for (; i < n4; i += stride) {
    f4 v = reinterpret_cast<const f4*>(in)[i];
    s4 o;
#pragma unroll
    for (int j = 0; j < 4; ++j) o[j] = (short)f2bf(v[j]);
    reinterpret_cast<s4*>(out)[i] = o;
  }
}

__global__ void embed_gather(const int* __restrict__ x, const float* __restrict__ emb,
                             u16* __restrict__ A) {
  int m = blockIdx.x;                 // m = b*SEQ + t
  long base = (long)x[m] * EMB;
  int e4 = threadIdx.x;               // 0..127, 4 elems each
  f4 v = reinterpret_cast<const f4*>(emb + base)[e4];
  s4 o;
#pragma unroll
  for (int j = 0; j < 4; ++j) o[j] = (short)f2bf(v[j]);
  reinterpret_cast<s4*>(A + (long)m * EMB)[e4] = o;
}

static __device__ __forceinline__ void gload_lds16(const void* g, void* l) {
  __builtin_amdgcn_global_load_lds(
      (const __attribute__((address_space(1))) void*)g,
      (__attribute__((address_space(3))) void*)l, 16, 0, 0);
}

// C = A*B^T + bias, 128x128 tile, BK=64, swizzled staging, bijective XCD
// grid swizzle. TXG=1: out row = t*BATCH + b (time-major xg).  [r10-validated]
template<int TXG>
__global__ __launch_bounds__(256) void gemm_bt(
    const u16* __restrict__ A, const u16* __restrict__ B,
    const float* __restrict__ bias, float* __restrict__ C,
    int M, int N, int K)
{
  __shared__ u16 As[128 * 64];
  __shared__ u16 Bs[128 * 64];
  int tid  = threadIdx.x;
  int lane = tid & 63;
  int wid  = tid >> 6;

  int nwg = gridDim.x * gridDim.y;
  int id  = blockIdx.y * gridDim.x + blockIdx.x;
  int id2 = (id & 7) * (nwg >> 3) + (id >> 3);
  int bx  = id2 % gridDim.x, by = id2 / gridDim.x;
  int m0 = by * 128, n0 = bx * 128;

  int wm = (wid >> 1) * 64, wn = (wid & 1) * 64;
  int r  = lane & 15;
  int hi = lane >> 4;
  f32x4 acc[4][4] = {};

  const u16* gaj[4];
  const u16* gbj[4];
  u16* laj[4];
  u16* lbj[4];
#pragma unroll
  for (int j = 0; j < 4; ++j) {
    int c   = wid * 256 + j * 64 + lane;
    int row = c >> 3;
    int gl  = (c & 7) ^ (row & 7);
    gaj[j] = A + (long)(m0 + row) * K + gl * 8;
    gbj[j] = B + (long)(n0 + row) * K + gl * 8;
    laj[j] = As + wid * 2048 + j * 512;
    lbj[j] = Bs + wid * 2048 + j * 512;
  }

  for (int kt = 0; kt < K; kt += 64) {
    __syncthreads();
#pragma unroll
    for (int j = 0; j < 4; ++j) {
      gload_lds16(gaj[j] + kt, laj[j]);
      gload_lds16(gbj[j] + kt, lbj[j]);
    }
    __syncthreads();
    short8 af[2][4], bf[2][4];
#pragma unroll
    for (int ks = 0; ks < 2; ++ks)
#pragma unroll
      for (int i = 0; i < 4; ++i) {
        int ra = wm + i * 16 + r;
        int rb = wn + i * 16 + r;
        af[ks][i] = *reinterpret_cast<const short8*>(
            &As[ra * 64 + ((ks * 4 + hi) ^ (ra & 7)) * 8]);
        bf[ks][i] = *reinterpret_cast<const short8*>(
            &Bs[rb * 64 + ((ks * 4 + hi) ^ (rb & 7)) * 8]);
      }
#pragma unroll
    for (int ks = 0; ks < 2; ++ks)
#pragma unroll
      for (int i = 0; i < 4; ++i)
#pragma unroll
        for (int j = 0; j < 4; ++j)
          acc[i][j] = __builtin_amdgcn_mfma_f32_16x16x32_bf16(
              af[ks][i], bf[ks][j], acc[i][j], 0, 0, 0);
  }

#pragma unroll
  for (int i = 0; i < 4; ++i) {
    int m = m0 + wm + i * 16 + (hi << 2);
#pragma unroll
    for (int j = 0; j < 4; ++j) {
      int n = n0 + wn + j * 16 + r;
      float bv = bias[n];
#pragma unroll
      for (int jj = 0; jj < 4; ++jj) {
        int mm = m + jj;
        long row;
        if constexpr (TXG) {
          row = (long)(mm & (SEQ - 1)) * BATCH + (mm >> 8);  // t*B + b
        } else {
          row = mm;
        }
        C[row * N + n] = acc[i][j][jj] + bv;
      }
    }
  }
}

// ============ LSTM variant A: sentinel-arena (tagless, half the coherent
// requests of the tagged path). Write-once per-step buffers (no WAR, no
// double-buffer); arena memset 0xFF per launch; a 16B load is valid iff no
// u16 is 0xFFFF (f2bf of |h|<1 can't emit it) — fail-closed retry.
__global__ __launch_bounds__(256, 1) void lstm_arena(
    const float* __restrict__ xg, const u16* __restrict__ Whh,
    const float* __restrict__ b_hh, char* __restrict__ hsb,
    u16* __restrict__ h_all)
{
  __shared__ float part[4][4][16][17];
  __shared__ u16 htile[16][16];

  int tid = threadIdx.x;
  int w = tid >> 6, lane = tid & 63;
  int bid = blockIdx.x;
  int col0 = bid * 16;
  int r  = lane & 15;
  int ko = (lane >> 4) << 3;          // 0,8,16,24

  short8 Wf[8][4];
#pragma unroll
  for (int kk8 = 0; kk8 < 8; ++kk8)
#pragma unroll
    for (int g = 0; g < 4; ++g)
      Wf[kk8][g] = *reinterpret_cast<const short8*>(
          Whh + (long)(g * HID + col0 + r) * HID + (w * 256 + kk8 * 32 + ko));

  // consumer chunk offsets: k = w*256 + (ph*4+kk)*32 + ko
  // producer p = k>>4; in-slab byte = r*32 + (k&15)*2
  unsigned coff[2][4];
#pragma unroll
  for (int ph = 0; ph < 2; ++ph)
#pragma unroll
    for (int kk = 0; kk < 4; ++kk) {
      int p = w * 16 + (ph * 4 + kk) * 2 + (ko >> 4);
      coff[ph][kk] = (unsigned)(p * SLAB2 + r * 32 + (ko & 15) * 2);
    }

  int eb = tid >> 4, ec = tid & 15;
  const float* xgp = xg + (long)eb * GDIM + col0 + ec;
  float bias4[4];
#pragma unroll
  for (int g = 0; g < 4; ++g) bias4[g] = b_hh[g * HID + col0 + ec];
  u16* hap = h_all + (long)eb * SEQ * HID + col0 + ec;
  float creg = 0.f;

  // publish h(0)=0 into step-0 buffer (32 x 16B zero stores)
  if (tid < 32) {
    short8 z = {};
    void* dst = hsb + (size_t)bid * SLAB2 + tid * 16;
    asm volatile("global_store_dwordx4 %0, %1, off sc1" :: "v"(dst), "v"(z) : "memory");
  }

  float xv[4];
#pragma unroll
  for (int g = 0; g < 4; ++g) xv[g] = xgp[g * HID];

  for (int t = 0; t < SEQ; ++t) {
    const char* hb = hsb + (size_t)t * STEPB2;

    f32x4 a0 = {}, a1 = {}, a2 = {}, a3 = {};
#pragma unroll
    for (int ph = 0; ph < 2; ++ph) {
      u32x4 q[4];
      for (;;) {
#pragma unroll
        for (int kk = 0; kk < 4; ++kk)
          asm volatile("global_load_dwordx4 %0, %1, off sc1"
                       : "=v"(q[kk]) : "v"(hb + coff[ph][kk]));
        asm volatile("s_waitcnt vmcnt(0)" ::: "memory");
        __builtin_amdgcn_sched_barrier(0);
        bool ok = true;
#pragma unroll
        for (int kk = 0; kk < 4; ++kk)
#pragma unroll
          for (int j = 0; j < 4; ++j) {
            unsigned v = q[kk][j];
            ok = ok && ((v & 0xffffu) != 0xffffu) && ((v >> 16) != 0xffffu);
          }
        if (__all(ok)) break;
        __builtin_amdgcn_s_sleep(1);
      }
#pragma unroll
      for (int kk = 0; kk < 4; ++kk) {
        short8 av = __builtin_bit_cast(short8, q[kk]);
        a0 = __builtin_amdgcn_mfma_f32_16x16x32_bf16(av, Wf[ph * 4 + kk][0], a0, 0, 0, 0);
        a1 = __builtin_amdgcn_mfma_f32_16x16x32_bf16(av, Wf[ph * 4 + kk][1], a1, 0, 0, 0);
        a2 = __builtin_amdgcn_mfma_f32_16x16x32_bf16(av, Wf[ph * 4 + kk][2], a2, 0, 0, 0);
        a3 = __builtin_amdgcn_mfma_f32_16x16x32_bf16(av, Wf[ph * 4 + kk][3], a3, 0, 0, 0);
      }
    }

#pragma unroll
    for (int j = 0; j < 4; ++j) {
      int batch = ((lane >> 4) << 2) + j;
      part[w][0][batch][r] = a0[j];
      part[w][1][batch][r] = a1[j];
      part[w][2][batch][r] = a2[j];
      part[w][3][batch][r] = a3[j];
    }
    __syncthreads();                       // (A) partials + h(t) reads done

    float pre[4];
#pragma unroll
    for (int g = 0; g < 4; ++g)
      pre[g] = part[0][g][eb][ec] + part[1][g][eb][ec] +
               part[2][g][eb][ec] + part[3][g][eb][ec] + xv[g] + bias4[g];
    float i_ = fsig(pre[0]);
    float f_ = fsig(pre[1]);
    float g_ = ftanh(pre[2]);
    float o_ = fsig(pre[3]);
    float cn = f_ * creg + i_ * g_;
    creg = cn;
    u16 hbf = f2bf(o_ * ftanh(cn));
    htile[eb][ec] = hbf;
    __syncthreads();                       // (B) htile complete

    if (t + 1 < SEQ && tid < 32) {         // publish h(t+1), fire-and-forget
      short8 v = *reinterpret_cast<const short8*>(
          reinterpret_cast<const u16*>(htile) + tid * 8);
      void* dst = hsb + (size_t)(t + 1) * STEPB2 + (size_t)bid * SLAB2 + tid * 16;
      asm volatile("global_store_dwordx4 %0, %1, off sc1" :: "v"(dst), "v"(v) : "memory");
    }

    hap[(long)t * HID] = hbf;
    int tn = (t + 1 < SEQ) ? t + 1 : t;
#pragma unroll
    for (int g = 0; g < 4; ++g)
      xv[g] = xgp[(long)tn * BATCH * GDIM + g * HID];
    // no end barrier: write-once buffers, htile WAR ordered by sync(A)@t+1
  }
}

// ============ LSTM variant B: r10 tagged (proven fallback) ==============
__global__ __launch_bounds__(256, 1) void lstm_persist(
    const float* __restrict__ xg, const u16* __restrict__ Whh,
    const float* __restrict__ b_hh, unsigned* __restrict__ h_buf,
    u16* __restrict__ h_all)
{
  __shared__ float part[4][4][16][17];

  int tid = threadIdx.x;
  int w = tid >> 6, lane = tid & 63;
  int bid = blockIdx.x;
  int col0 = bid * 16;
  int r  = lane & 15;
  int ko = (lane >> 4) << 3;

  short8 Wf[8][4];
#pragma unroll
  for (int kk8 = 0; kk8 < 8; ++kk8)
#pragma unroll
    for (int g = 0; g < 4; ++g)
      Wf[kk8][g] = *reinterpret_cast<const short8*>(
          Whh + (long)(g * HID + col0 + r) * HID + (w * 256 + kk8 * 32 + ko));

  unsigned soff[2][4];
#pragma unroll
  for (int ph = 0; ph < 2; ++ph)
#pragma unroll
    for (int kk = 0; kk < 4; ++kk) {
      int p = w * 16 + ph * 8 + kk * 2 + (ko >> 4);
      soff[ph][kk] = (unsigned)(p * SLAB + r * 64 + (ko & 8) * 4);
    }
  const char* hbase = reinterpret_cast<const char*>(h_buf);

  int eb = tid >> 4, ec = tid & 15;
  const float* xgp = xg + (long)eb * GDIM + col0 + ec;
  float bias4[4];
#pragma unroll
  for (int g = 0; g < 4; ++g) bias4[g] = b_hh[g * HID + col0 + ec];
  u16* hap = h_all + (long)eb * SEQ * HID + col0 + ec;
  float creg = 0.f;

  __hip_atomic_store(&h_buf[(bid * SLAB / 4) + tid], 1u << 16,
                     __ATOMIC_RELAXED, __HIP_MEMORY_SCOPE_AGENT);

  float xv[4];
#pragma unroll
  for (int g = 0; g < 4; ++g) xv[g] = xgp[g * HID];

  for (int t = 0; t < SEQ; ++t) {
    unsigned want = (unsigned)(t + 1);
    const char* hb = hbase + ((t & 1) ? BUFB : 0);

    f32x4 a0 = {}, a1 = {}, a2 = {}, a3 = {};
#pragma unroll
    for (int ph = 0; ph < 2; ++ph) {
      u32x4 q[4][2];
      for (;;) {
#pragma unroll
        for (int kk = 0; kk < 4; ++kk) {
          const void* a = hb + soff[ph][kk];
          const void* b = hb + soff[ph][kk] + 16;
          asm volatile("global_load_dwordx4 %0, %1, off sc1"
                       : "=v"(q[kk][0]) : "v"(a));
          asm volatile("global_load_dwordx4 %0, %1, off sc1"
                       : "=v"(q[kk][1]) : "v"(b));
        }
        asm volatile("s_waitcnt vmcnt(0)" ::: "memory");
        __builtin_amdgcn_sched_barrier(0);
        bool allok = true;
#pragma unroll
        for (int kk = 0; kk < 4; ++kk)
#pragma unroll
          for (int v = 0; v < 2; ++v)
#pragma unroll
            for (int j = 0; j < 4; ++j)
              allok = allok && ((q[kk][v][j] >> 16) >= want);
        if (__all(allok)) break;
        __builtin_amdgcn_s_sleep(1);
      }
#pragma unroll
      for (int kk = 0; kk < 4; ++kk) {
        u32x4 wv;
        wv[0] = (q[kk][0][0] & 0xffffu) | (q[kk][0][1] << 16);
        wv[1] = (q[kk][0][2] & 0xffffu) | (q[kk][0][3] << 16);
        wv[2] = (q[kk][1][0] & 0xffffu) | (q[kk][1][1] << 16);
        wv[3] = (q[kk][1][2] & 0xffffu) | (q[kk][1][3] << 16);
        short8 av = __builtin_bit_cast(short8, wv);
        a0 = __builtin_amdgcn_mfma_f32_16x16x32_bf16(av, Wf[ph * 4 + kk][0], a0, 0, 0, 0);
        a1 = __builtin_amdgcn_mfma_f32_16x16x32_bf16(av, Wf[ph * 4 + kk][1], a1, 0, 0, 0);
        a2 = __builtin_amdgcn_mfma_f32_16x16x32_bf16(av, Wf[ph * 4 + kk][2], a2, 0, 0, 0);
        a3 = __builtin_amdgcn_mfma_f32_16x16x32_bf16(av, Wf[ph * 4 + kk][3], a3, 0, 0, 0);
      }
    }

#pragma unroll
    for (int j = 0; j < 4; ++j) {
      int batch = ((lane >> 4) << 2) + j;
      part[w][0][batch][r] = a0[j];
      part[w][1][batch][r] = a1[j];
      part[w][2][batch][r] = a2[j];
      part[w][3][batch][r] = a3[j];
    }
    __syncthreads();

    float pre[4];
#pragma unroll
    for (int g = 0; g < 4; ++g)
      pre[g] = part[0][g][eb][ec] + part[1][g][eb][ec] +
               part[2][g][eb][ec] + part[3][g][eb][ec] + xv[g] + bias4[g];
    float i_ = fsig(pre[0]);
    float f_ = fsig(pre[1]);
    float g_ = ftanh(pre[2]);
    float o_ = fsig(pre[3]);
    float cn = f_ * creg + i_ * g_;
    creg = cn;
    u16 hbf = f2bf(o_ * ftanh(cn));

    if (t + 1 < SEQ) {
      unsigned word = (unsigned)hbf | ((unsigned)(t + 2) << 16);
      __hip_atomic_store(
          &h_buf[(((t + 1) & 1) ? BUFB / 4 : 0) + (bid * SLAB / 4) + tid],
          word, __ATOMIC_RELAXED, __HIP_MEMORY_SCOPE_AGENT);
    }

    hap[(long)t * HID] = hbf;
    int tn = (t + 1 < SEQ) ? t + 1 : t;
#pragma unroll
    for (int g = 0; g < 4; ++g)
      xv[g] = xgp[(long)tn * BATCH * GDIM + g * HID];

    __syncthreads();
  }
}

extern "C" void kernel_launch(void* const* d_in, const int* in_sizes, int n_in,
                              void* d_out, int out_size, void* d_ws, size_t ws_size,
                              hipStream_t stream) {
  const int*   x      = (const int*)d_in[0];
  const float* emb    = (const float*)d_in[1];
  const float* W_ih   = (const float*)d_in[2];
  const float* W_hh   = (const float*)d_in[3];
  const float* b_ih   = (const float*)d_in[4];
  const float* b_hh   = (const float*)d_in[5];
  const float* head_W = (const float*)d_in[6];
  const float* head_b = (const float*)d_in[7];
  float* out = (float*)d_out;

  char* ws = (char*)d_ws;
  size_t off = 0;
  auto alloc = [&](size_t bytes) -> void* {
    void* p = ws + off;
    off += (bytes + 255) & ~(size_t)255;
    return p;
  };
  u16*   Aemb  = (u16*)alloc((size_t)MTOT * EMB * 2);
  u16*   Wih_b = (u16*)alloc((size_t)GDIM * EMB * 2);
  u16*   Whh_b = (u16*)alloc((size_t)GDIM * HID * 2);
  u16*   HW_b  = (u16*)alloc((size_t)VOCAB * HID * 2);
  float* xg    = (float*)alloc((size_t)MTOT * GDIM * 4);   // time-major [T][B][4H]
  u16*   h_all = (u16*)alloc((size_t)MTOT * HID * 2);

  // choose exchange protocol by workspace capacity (r9's failure was the
  // 182.6MB overflow; the check makes the arena safe to attempt)
  size_t off_arena = off;
  bool use_arena = (off_arena + ARENAB + 256 <= ws_size);

  cvt_bf16_v4<<<1024, 256, 0, stream>>>(W_ih, Wih_b, (long)GDIM * EMB / 4);
  cvt_bf16_v4<<<1024, 256, 0, stream>>>(W_hh, Whh_b, (long)GDIM * HID / 4);
  cvt_bf16_v4<<<2048, 256, 0, stream>>>(head_W, HW_b, (long)VOCAB * HID / 4);
  embed_gather<<<MTOT, 128, 0, stream>>>(x, emb, Aemb);

  gemm_bt<1><<<dim3(GDIM / 128, MTOT / 128), 256, 0, stream>>>(
      Aemb, Wih_b, b_ih, xg, MTOT, GDIM, EMB);

  if (use_arena) {
    char* hsb = (char*)alloc(ARENAB);
    hipMemsetAsync(hsb, 0xFF, ARENAB, stream);   // sentinels (also clears
                                                 // stale prior-replay h)
    lstm_arena<<<dim3(NBLK), dim3(256), 0, stream>>>(
        xg, Whh_b, b_hh, hsb, h_all);
  } else {
    unsigned* h_buf = (unsigned*)alloc((size_t)2 * BUFB);
    hipMemsetAsync(h_buf, 0, (size_t)2 * BUFB, stream);   // tags fail closed
    lstm_persist<<<dim3(NBLK), dim3(256), 0, stream>>>(
        xg, Whh_b, b_hh, h_buf, h_all);
  }

  gemm_bt<0><<<dim3(VOCAB / 128, MTOT / 128), 256, 0, stream>>>(
      h_all, HW_b, head_b, out, MTOT, VOCAB, HID);
}